// Round 2
// baseline (204.705 us; speedup 1.0000x reference)
//
#include <hip/hip_runtime.h>

// ---------------------------------------------------------------------------
// 3-kernel fused temporal MHA (MI355X / gfx950).
// B=256, S=176 (8 time * 22 joints), D_in=128, H=8, Hd=32.
//  K0: W fp32 -> WT bf16 [3][8][32][128]          (once, tiny)
//  K1: QKV projection per (b, m-tile): Q,K row-major bf16, V transposed bf16
//      Q pre-scaled by log2(e)/sqrt(32); V has ReLU; VT t-padded to 192 w/ 0.
//  K2: attention, one wave per (b,h,row-tile). No barriers. Only P goes
//      through (private, per-wave) LDS for the C->A layout transform.
// ---------------------------------------------------------------------------

#define SEQ    176
#define HD     32
#define DIN    128
#define DMODEL 256
#define VTPAD  192   // t dimension padded to 192 for the K=192 PV loop

typedef unsigned short ushort_t;
typedef __attribute__((ext_vector_type(8))) short short8;
typedef __attribute__((ext_vector_type(4))) float float4v;

// ws layout (bytes):
#define WS_WT 0u          // 3*8*32*128 bf16 = 196608 B
#define WS_Q  262144u     // 2048*176*32 bf16 = 23068672 B
#define WS_K  23330816u   // same
#define WS_VT 46399488u   // 2048*32*192 bf16 = 25165824 B  (end 71565312)

__device__ __forceinline__ ushort_t f2bf(float f) {
    union { float f; unsigned int u; } c; c.f = f;
    unsigned int u = c.u;
    unsigned int rb = 0x7FFFu + ((u >> 16) & 1u);   // round-to-nearest-even
    return (ushort_t)((u + rb) >> 16);
}

// ---------------- K0: W -> WT bf16 [mat][h][n][k] -------------------------
__global__ __launch_bounds__(256)
void k0_wconv(const float* __restrict__ Wq, const float* __restrict__ Wk,
              const float* __restrict__ Wv, ushort_t* __restrict__ WT)
{
    int idx = blockIdx.x * 256 + threadIdx.x;   // 98304 exact
    int k   = idx & 127;
    int n   = (idx >> 7) & 31;
    int h   = (idx >> 12) & 7;
    int mat = idx >> 15;
    const float* W = (mat == 0) ? Wq : ((mat == 1) ? Wk : Wv);
    WT[idx] = f2bf(W[k * DMODEL + h * HD + n]);
}

// ---------------- K1: QKV projection --------------------------------------
// grid = 256*11 blocks of 256 threads. Block (b, mt): 16 x-rows, all 48
// (mat,h,nt) n-tile jobs, 12 per wave. K=128 in 4 MFMA steps.
__global__ __launch_bounds__(256, 6)
void k1_qkv(const float* __restrict__ x, const ushort_t* __restrict__ WT,
            const float* __restrict__ bq, const float* __restrict__ bk,
            const float* __restrict__ bv,
            ushort_t* __restrict__ Qg, ushort_t* __restrict__ Kg,
            ushort_t* __restrict__ VTg)
{
    __shared__ ushort_t XS[16 * 136];           // 16 rows x 128 (+8 pad)
    const int tid = threadIdx.x;
    const int lane = tid & 63, wave = tid >> 6;
    const int c = lane & 15, q = lane >> 4;
    const int b = blockIdx.x / 11, mt = blockIdx.x % 11;

    // stage x-tile -> bf16 LDS (512 float4 = 2/thread)
    const float* xrow = x + ((size_t)b * SEQ + mt * 16) * DIN;
#pragma unroll
    for (int it = 0; it < 2; ++it) {
        int f4 = tid + it * 256;
        int flat = f4 * 4, row = flat >> 7, col = flat & 127;
        float4 v = reinterpret_cast<const float4*>(xrow)[f4];
        ushort_t* d = XS + row * 136 + col;
        d[0] = f2bf(v.x); d[1] = f2bf(v.y); d[2] = f2bf(v.z); d[3] = f2bf(v.w);
    }
    __syncthreads();

    // X A-fragments: shared by all 12 jobs of this wave
    short8 afr[4];
#pragma unroll
    for (int kk = 0; kk < 4; ++kk)
        afr[kk] = *reinterpret_cast<const short8*>(XS + c * 136 + kk * 32 + q * 8);

    const float qscale = 0.17677669529663687f * 1.4426950408889634f; // 1/sqrt(32)*log2e

    for (int i = 0; i < 12; ++i) {
        int j = wave * 12 + i;                   // 0..47 (wave-uniform)
        int mat = j >> 4, rem = j & 15, h = rem >> 1, nt = rem & 1;
        const ushort_t* wrow =
            WT + (size_t)(((mat * 8 + h) * 32) + nt * 16 + c) * 128 + q * 8;
        float4v acc = {0.f, 0.f, 0.f, 0.f};
        if (mat == 2) {                          // V^T = (Wv^T)(X^T): swap A/B
#pragma unroll
            for (int kk = 0; kk < 4; ++kk) {
                short8 bf = *reinterpret_cast<const short8*>(wrow + kk * 32);
                acc = __builtin_amdgcn_mfma_f32_16x16x32_bf16(bf, afr[kk], acc, 0, 0, 0);
            }
        } else {
#pragma unroll
            for (int kk = 0; kk < 4; ++kk) {
                short8 bf = *reinterpret_cast<const short8*>(wrow + kk * 32);
                acc = __builtin_amdgcn_mfma_f32_16x16x32_bf16(afr[kk], bf, acc, 0, 0, 0);
            }
        }
        int bh = b * 8 + h;
        if (mat == 2) {
            // C: col=c -> t within m-tile, row=q*4+r -> d within n-tile
#pragma unroll
            for (int r = 0; r < 4; ++r) {
                int d = nt * 16 + q * 4 + r;
                float v = acc[r] + bv[h * HD + d];
                v = v > 0.f ? v : 0.f;           // ReLU on V
                VTg[((size_t)bh * HD + d) * VTPAD + mt * 16 + c] = f2bf(v);
            }
        } else if (mat == 0) {
            float bia = bq[h * HD + nt * 16 + c];
#pragma unroll
            for (int r = 0; r < 4; ++r) {
                int t = mt * 16 + q * 4 + r;
                Qg[((size_t)bh * SEQ + t) * HD + nt * 16 + c] = f2bf((acc[r] + bia) * qscale);
            }
        } else {
            float bia = bk[h * HD + nt * 16 + c];
#pragma unroll
            for (int r = 0; r < 4; ++r) {
                int t = mt * 16 + q * 4 + r;
                Kg[((size_t)bh * SEQ + t) * HD + nt * 16 + c] = f2bf(acc[r] + bia);
            }
        }
    }

    // mt==10 blocks also zero VT's t-pad [176,192) for all 8 heads of b
    if (mt == 10) {
#pragma unroll
        for (int it = 0; it < 16; ++it) {
            int idx = tid + it * 256;            // < 4096
            int h = idx >> 9, d = (idx >> 4) & 31, t = 176 + (idx & 15);
            VTg[((size_t)(b * 8 + h) * HD + d) * VTPAD + t] = 0;
        }
    }
}

// ---------------- K2: attention -------------------------------------------
// grid = 5632 blocks of 256 threads; flat wave-job id = blockIdx*4+wave,
// id -> (bh = id/11, row-tile w = id%11). No __syncthreads anywhere.
__global__ __launch_bounds__(256, 4)
void k2_attn(const ushort_t* __restrict__ Qg, const ushort_t* __restrict__ Kg,
             const ushort_t* __restrict__ VTg, float* __restrict__ out)
{
    __shared__ ushort_t P[4 * 16 * 200];        // per-wave 16x200 (25.6 KB)
    const int tid = threadIdx.x;
    const int lane = tid & 63, wave = tid >> 6;
    const int c = lane & 15, q = lane >> 4;
    const int id = blockIdx.x * 4 + wave;       // 0..22527
    const int bh = id / 11, w = id - bh * 11;
    const int b = bh >> 3, h = bh & 7;

    const ushort_t* Qp = Qg + (size_t)bh * (SEQ * HD);
    const ushort_t* Kp = Kg + (size_t)bh * (SEQ * HD);
    const ushort_t* Vp = VTg + (size_t)bh * (HD * VTPAD);

    // QK^T: scores tile [16 x 176], K=32 -> 1 MFMA per n-tile
    short8 afrag = *reinterpret_cast<const short8*>(Qp + (w * 16 + c) * HD + q * 8);
    float4v sc[11];
#pragma unroll
    for (int n = 0; n < 11; ++n) {
        short8 bf = *reinterpret_cast<const short8*>(Kp + (n * 16 + c) * HD + q * 8);
        float4v z = {0.f, 0.f, 0.f, 0.f};
        sc[n] = __builtin_amdgcn_mfma_f32_16x16x32_bf16(afrag, bf, z, 0, 0, 0);
    }

    // mask: same 22-joint time-block, off-diagonal -> -inf
    int cb[11];
#pragma unroll
    for (int n = 0; n < 11; ++n) cb[n] = (n * 16 + c) / 22;
#pragma unroll
    for (int r = 0; r < 4; ++r) {
        int rg = w * 16 + q * 4 + r;
        int rb = rg / 22;
#pragma unroll
        for (int n = 0; n < 11; ++n) {
            int cg = n * 16 + c;
            if (cb[n] == rb && cg != rg) sc[n][r] = -1e30f;
        }
    }

    // softmax in exp2 domain (log2e folded into Q; scores ~N(0,1) so no
    // max-subtract needed). Keep P unnormalized; fold 1/sum into epilogue.
    float inv[4];
#pragma unroll
    for (int r = 0; r < 4; ++r) {
        float s = 0.f;
#pragma unroll
        for (int n = 0; n < 11; ++n) {
            float e = __builtin_amdgcn_exp2f(sc[n][r]);
            sc[n][r] = e;
            s += e;
        }
        s += __shfl_xor(s, 1, 64);
        s += __shfl_xor(s, 2, 64);
        s += __shfl_xor(s, 4, 64);
        s += __shfl_xor(s, 8, 64);
        inv[r] = 1.0f / s;
    }

    // P (C-layout regs) -> per-wave LDS row-major [16][200], pad cols zeroed
    ushort_t* psw = P + wave * 3200;
#pragma unroll
    for (int n = 0; n < 11; ++n)
#pragma unroll
        for (int r = 0; r < 4; ++r)
            psw[(q * 4 + r) * 200 + n * 16 + c] = f2bf(sc[n][r]);
#pragma unroll
    for (int it = 0; it < 4; ++it) {
        int idx = lane + it * 64;                // 256: rows x pad cols [176,192)
        psw[(idx >> 4) * 200 + 176 + (idx & 15)] = 0;
    }
    // same-wave LDS RAW: compiler inserts lgkmcnt wait; no barrier needed.

    // PV: O[t_row][d] tile [16 x 32], K = 192 in 6 steps; B = VT rows (global)
    float4v o0 = {0.f, 0.f, 0.f, 0.f}, o1 = {0.f, 0.f, 0.f, 0.f};
#pragma unroll
    for (int kk = 0; kk < 6; ++kk) {
        short8 pa = *reinterpret_cast<const short8*>(psw + c * 200 + kk * 32 + q * 8);
        short8 v0 = *reinterpret_cast<const short8*>(Vp + c * VTPAD + kk * 32 + q * 8);
        short8 v1 = *reinterpret_cast<const short8*>(Vp + (16 + c) * VTPAD + kk * 32 + q * 8);
        o0 = __builtin_amdgcn_mfma_f32_16x16x32_bf16(pa, v0, o0, 0, 0, 0);
        o1 = __builtin_amdgcn_mfma_f32_16x16x32_bf16(pa, v1, o1, 0, 0, 0);
    }

    float* ob = out + ((size_t)b * SEQ + w * 16) * DMODEL + h * HD;
#pragma unroll
    for (int r = 0; r < 4; ++r) {
        ob[(q * 4 + r) * DMODEL + c]      = o0[r] * inv[r];
        ob[(q * 4 + r) * DMODEL + 16 + c] = o1[r] * inv[r];
    }
}

extern "C" void kernel_launch(void* const* d_in, const int* in_sizes, int n_in,
                              void* d_out, int out_size, void* d_ws, size_t ws_size,
                              hipStream_t stream) {
    const float* x  = (const float*)d_in[0];
    const float* Wq = (const float*)d_in[1];
    const float* bq = (const float*)d_in[2];
    const float* Wk = (const float*)d_in[3];
    const float* bk = (const float*)d_in[4];
    const float* Wv = (const float*)d_in[5];
    const float* bv = (const float*)d_in[6];
    float* out = (float*)d_out;

    char* ws = (char*)d_ws;
    ushort_t* WT  = (ushort_t*)(ws + WS_WT);
    ushort_t* Qg  = (ushort_t*)(ws + WS_Q);
    ushort_t* Kg  = (ushort_t*)(ws + WS_K);
    ushort_t* VTg = (ushort_t*)(ws + WS_VT);

    k0_wconv<<<dim3(384), dim3(256), 0, stream>>>(Wq, Wk, Wv, WT);
    k1_qkv<<<dim3(256 * 11), dim3(256), 0, stream>>>(x, WT, bq, bk, bv, Qg, Kg, VTg);
    k2_attn<<<dim3(5632), dim3(256), 0, stream>>>(Qg, Kg, VTg, out);
}

// Round 5
// 142.268 us; speedup vs baseline: 1.4389x; 1.4389x over previous
//
#include <hip/hip_runtime.h>

// ---------------------------------------------------------------------------
// Temporal MHA (MI355X/gfx950), B=256, S=176 (8t x 22j), D_in=128, H=8, Hd=32.
//  k0: x,W -> bf16 once (ws).
//  k1 (fused, per (b,h) block, 704 thr = 11 waves, 2 blocks/CU):
//    phase1: wave w owns m-tile w; x A-frags direct from global bf16 (reused
//            across 6 QKV jobs); W B-frags from padded LDS; Q/K/VT -> LDS.
//    phase2: wave w owns row-tile w; QK MFMA, mask, exp2-softmax
//            (unnormalized P, 1/sum folded into epilogue), P->LDS (aliased
//            over WS/QS/KS behind a barrier), PV MFMA, fp32 store.
// R4 fix: W-staging chunk decode (16 chunks / 128-elem row).
// R5 fix: MISSING BARRIER between cross-wave W staging and phase-1 WS reads
//         (waves read W rows staged by other waves -> garbage -> NaN).
// ---------------------------------------------------------------------------

#define SEQ    176
#define HD     32
#define DIN    128
#define DMODEL 256

typedef unsigned short ushort_t;
typedef __attribute__((ext_vector_type(8))) short short8;
typedef __attribute__((ext_vector_type(4))) float float4v;
typedef __attribute__((ext_vector_type(4))) unsigned short ushort4v;

// ws layout (bytes): WT bf16 [3][8][32][128] @ 0; X16 bf16 [256*176*128] @ 196608
#define WS_WT 0u
#define WS_X  196608u

// LDS layout (ushort units), total 40192 ushort = 80384 B  (2 blocks/CU)
//  WS @ 0      [3][32][136] = 13056   } phase 1
//  QS @ 13056  [176][40]    = 7040    } written p1, read early p2
//  KS @ 20096  [176][40]    = 7040    } written p1, read early p2
//  P  @ 0      [11][16][192]= 33792     phase 2 (aliases WS/QS/KS, post-barrier)
//  VT @ 33792  [32][200]    = 6400      written p1, read late p2 (not aliased)
#define SMEM_TOTAL 40192
#define OFF_QS 13056
#define OFF_KS 20096
#define OFF_VT 33792
#define P_STRIDE 3072   // 16*192

__device__ __forceinline__ ushort_t f2bf(float f) {
    union { float f; unsigned int u; } c; c.f = f;
    unsigned int u = c.u;
    unsigned int rb = 0x7FFFu + ((u >> 16) & 1u);   // RTNE
    return (ushort_t)((u + rb) >> 16);
}

// ---------------- k0: one-shot bf16 conversion ----------------------------
// blocks [0,5632): x float4 -> short4 (1441792 float4 exact)
// blocks [5632,5728): W -> WT[mat][h][n][k] (24576 threads x 4 k-elems)
__global__ __launch_bounds__(256)
void k0_conv(const float* __restrict__ x,
             const float* __restrict__ Wq, const float* __restrict__ Wk,
             const float* __restrict__ Wv,
             ushort_t* __restrict__ WT, ushort_t* __restrict__ X16)
{
    int bid = blockIdx.x;
    if (bid < 5632) {
        int f4 = bid * 256 + threadIdx.x;
        float4 v = reinterpret_cast<const float4*>(x)[f4];
        ushort4v o;
        o.x = f2bf(v.x); o.y = f2bf(v.y); o.z = f2bf(v.z); o.w = f2bf(v.w);
        reinterpret_cast<ushort4v*>(X16)[f4] = o;
    } else {
        int idx = (bid - 5632) * 256 + threadIdx.x;   // < 24576
        int e = idx * 4;
        int mat = e >> 15, h = (e >> 12) & 7, n = (e >> 7) & 31, k = e & 127;
        const float* W = (mat == 0) ? Wq : ((mat == 1) ? Wk : Wv);
        ushort4v o;
        o.x = f2bf(W[(k + 0) * DMODEL + h * HD + n]);
        o.y = f2bf(W[(k + 1) * DMODEL + h * HD + n]);
        o.z = f2bf(W[(k + 2) * DMODEL + h * HD + n]);
        o.w = f2bf(W[(k + 3) * DMODEL + h * HD + n]);
        reinterpret_cast<ushort4v*>(WT)[idx] = o;
    }
}

// ---------------- k1: fused attention -------------------------------------
__global__ __launch_bounds__(704, 6)
void k1_attn(const ushort_t* __restrict__ X16, const ushort_t* __restrict__ WT,
             const float* __restrict__ bq, const float* __restrict__ bk,
             const float* __restrict__ bv, float* __restrict__ out)
{
    __shared__ ushort_t smem[SMEM_TOTAL];
    ushort_t* WS = smem;                 // [3][32][136]
    ushort_t* QS = smem + OFF_QS;        // [176][40]
    ushort_t* KS = smem + OFF_KS;        // [176][40]
    ushort_t* VT = smem + OFF_VT;        // [32][200]

    const int tid  = threadIdx.x;
    const int lane = tid & 63;
    const int w    = tid >> 6;           // wave 0..10 = m-tile / row-tile
    const int c    = lane & 15;
    const int q    = lane >> 4;
    const int b    = blockIdx.x >> 3;
    const int h    = blockIdx.x & 7;

    // ---- stage W-slice (head h) into padded LDS ----
    // 3 mats x 32 n-rows x 128 k = 1536 chunks of 8 ushorts (16 B);
    // 16 chunks per n-row.
#pragma unroll
    for (int it = 0; it < 3; ++it) {
        int c8 = tid + it * 704;
        if (c8 < 1536) {
            int mat = c8 >> 9, rem = c8 & 511, n = rem >> 4, kc = rem & 15;
            short8 v = *reinterpret_cast<const short8*>(
                WT + (size_t)(((mat * 8 + h) * 32 + n) * 128 + kc * 8));
            *reinterpret_cast<short8*>(WS + (mat * 32 + n) * 136 + kc * 8) = v;
        }
    }
    // zero VT pad cols [176,192)
    if (tid < 512) {
        VT[(tid >> 4) * 200 + 176 + (tid & 15)] = 0;
    }
    __syncthreads();   // barrier 0 [R5 fix]: W staging is cross-wave

    // ---- phase 1: QKV for m-tile w (6 jobs: mat x nt), A-frags from global
    const ushort_t* xr = X16 + ((size_t)b * SEQ + w * 16 + c) * DIN;
    short8 afr[4];
#pragma unroll
    for (int kk = 0; kk < 4; ++kk)
        afr[kk] = *reinterpret_cast<const short8*>(xr + kk * 32 + q * 8);

    const float qscale = 0.17677669529663687f * 1.4426950408889634f; // 1/sqrt(32)*log2e

#pragma unroll
    for (int jj = 0; jj < 6; ++jj) {
        const int mat = jj >> 1, nt = jj & 1;
        const ushort_t* wrow = WS + (mat * 32 + nt * 16 + c) * 136 + q * 8;
        float4v acc = {0.f, 0.f, 0.f, 0.f};
        if (mat == 2) {                  // V^T: swap A/B so store is by d-row
#pragma unroll
            for (int kk = 0; kk < 4; ++kk) {
                short8 bf = *reinterpret_cast<const short8*>(wrow + kk * 32);
                acc = __builtin_amdgcn_mfma_f32_16x16x32_bf16(bf, afr[kk], acc, 0, 0, 0);
            }
        } else {
#pragma unroll
            for (int kk = 0; kk < 4; ++kk) {
                short8 bf = *reinterpret_cast<const short8*>(wrow + kk * 32);
                acc = __builtin_amdgcn_mfma_f32_16x16x32_bf16(afr[kk], bf, acc, 0, 0, 0);
            }
        }
        const float* bias = (mat == 0) ? bq : ((mat == 1) ? bk : bv);
        float bia = bias[h * HD + nt * 16 + c];
        if (mat == 2) {
#pragma unroll
            for (int r = 0; r < 4; ++r) {
                float v = acc[r] + bia;
                v = v > 0.f ? v : 0.f;                       // ReLU on V
                VT[(nt * 16 + q * 4 + r) * 200 + w * 16 + c] = f2bf(v);
            }
        } else if (mat == 0) {
#pragma unroll
            for (int r = 0; r < 4; ++r)
                QS[(w * 16 + q * 4 + r) * 40 + nt * 16 + c] =
                    f2bf((acc[r] + bia) * qscale);
        } else {
#pragma unroll
            for (int r = 0; r < 4; ++r)
                KS[(w * 16 + q * 4 + r) * 40 + nt * 16 + c] = f2bf(acc[r] + bia);
        }
    }
    __syncthreads();   // barrier 1: Q/K/VT complete

    // ---- phase 2: attention for row-tile w ----
    short8 afrag = *reinterpret_cast<const short8*>(QS + (w * 16 + c) * 40 + q * 8);
    float4v sc[11];
#pragma unroll
    for (int n = 0; n < 11; ++n) {
        short8 bf = *reinterpret_cast<const short8*>(KS + (n * 16 + c) * 40 + q * 8);
        float4v z = {0.f, 0.f, 0.f, 0.f};
        sc[n] = __builtin_amdgcn_mfma_f32_16x16x32_bf16(afrag, bf, z, 0, 0, 0);
    }

    // mask: same 22-joint time-block, off-diagonal -> -inf
    int cb[11];
#pragma unroll
    for (int n = 0; n < 11; ++n) cb[n] = (n * 16 + c) / 22;
#pragma unroll
    for (int r = 0; r < 4; ++r) {
        int rg = w * 16 + q * 4 + r;
        int rb = rg / 22;
#pragma unroll
        for (int n = 0; n < 11; ++n) {
            int cg = n * 16 + c;
            if (cb[n] == rb && cg != rg) sc[n][r] = -1e30f;
        }
    }

    // exp2-domain softmax (log2e folded into Q); unnormalized P + epilogue 1/sum
    float inv[4];
#pragma unroll
    for (int r = 0; r < 4; ++r) {
        float s = 0.f;
#pragma unroll
        for (int n = 0; n < 11; ++n) {
            float e = __builtin_amdgcn_exp2f(sc[n][r]);
            sc[n][r] = e;
            s += e;
        }
        s += __shfl_xor(s, 1, 64);
        s += __shfl_xor(s, 2, 64);
        s += __shfl_xor(s, 4, 64);
        s += __shfl_xor(s, 8, 64);
        inv[r] = 1.0f / s;
    }

    __syncthreads();   // barrier 2: all QS/KS reads done; P may alias them

    ushort_t* psw = smem + w * P_STRIDE;   // [16][192]
#pragma unroll
    for (int n = 0; n < 11; ++n)
#pragma unroll
        for (int r = 0; r < 4; ++r)
            psw[(q * 4 + r) * 192 + n * 16 + c] = f2bf(sc[n][r]);
#pragma unroll
    for (int it = 0; it < 4; ++it) {
        int idx = lane + it * 64;          // zero pad cols [176,192)
        psw[(idx >> 4) * 192 + 176 + (idx & 15)] = 0;
    }
    // same-wave LDS RAW below: in-order LDS pipe + compiler lgkmcnt waits.

    float4v o0 = {0.f, 0.f, 0.f, 0.f}, o1 = {0.f, 0.f, 0.f, 0.f};
    const ushort_t* prow = psw + c * 192;
    const ushort_t* v0p  = VT + c * 200;
    const ushort_t* v1p  = VT + (16 + c) * 200;
#pragma unroll
    for (int kk = 0; kk < 6; ++kk) {
        short8 pa = *reinterpret_cast<const short8*>(prow + kk * 32 + q * 8);
        short8 v0 = *reinterpret_cast<const short8*>(v0p + kk * 32 + q * 8);
        short8 v1 = *reinterpret_cast<const short8*>(v1p + kk * 32 + q * 8);
        o0 = __builtin_amdgcn_mfma_f32_16x16x32_bf16(pa, v0, o0, 0, 0, 0);
        o1 = __builtin_amdgcn_mfma_f32_16x16x32_bf16(pa, v1, o1, 0, 0, 0);
    }

    float* ob = out + ((size_t)b * SEQ + w * 16) * DMODEL + h * HD;
#pragma unroll
    for (int r = 0; r < 4; ++r) {
        ob[(q * 4 + r) * DMODEL + c]      = o0[r] * inv[r];
        ob[(q * 4 + r) * DMODEL + 16 + c] = o1[r] * inv[r];
    }
}

extern "C" void kernel_launch(void* const* d_in, const int* in_sizes, int n_in,
                              void* d_out, int out_size, void* d_ws, size_t ws_size,
                              hipStream_t stream) {
    const float* x  = (const float*)d_in[0];
    const float* Wq = (const float*)d_in[1];
    const float* bq = (const float*)d_in[2];
    const float* Wk = (const float*)d_in[3];
    const float* bk = (const float*)d_in[4];
    const float* Wv = (const float*)d_in[5];
    const float* bv = (const float*)d_in[6];
    float* out = (float*)d_out;

    char* ws = (char*)d_ws;
    ushort_t* WT  = (ushort_t*)(ws + WS_WT);
    ushort_t* X16 = (ushort_t*)(ws + WS_X);

    k0_conv<<<dim3(5728), dim3(256), 0, stream>>>(x, Wq, Wk, Wv, WT, X16);
    k1_attn<<<dim3(2048), dim3(704), 0, stream>>>(X16, WT, bq, bk, bv, out);
}

// Round 7
// 133.406 us; speedup vs baseline: 1.5345x; 1.0664x over previous
//
#include <hip/hip_runtime.h>

// ---------------------------------------------------------------------------
// Temporal MHA (MI355X/gfx950), B=256, S=176 (8t x 22j), D_in=128, H=8, Hd=32.
//  k0: x,W -> bf16 once (ws).
//  k1 (per (b,h) block, 704 thr = 11 waves):
//   p1: wave w = m-tile w. Q computed TRANSPOSED (A/B swap) -> stays in regs.
//       K -> KS LDS, V^T -> VT LDS. W B-frags from padded LDS.
//   p2: S^T = K·Q^T and O^T = V^T·P^T, both via 16x16x32 MFMA with a shared
//       k-slot permutation (slot(q,j) = j<4 ? q*4+j : 16+q*4+j-4), so Q and P
//       never touch LDS. Mask, exp2-softmax (unnormalized P, 1/sum folded
//       into epilogue), float4 stores.
//  R7: replaced unavailable 16x16x16 builtin (host-pass #error) with
//      permuted-K 16x16x32; all fragment orientations re-derived from R5's
//      verified K/VT layouts.
// ---------------------------------------------------------------------------

#define SEQ    176
#define HD     32
#define DIN    128
#define DMODEL 256

typedef unsigned short ushort_t;
typedef __attribute__((ext_vector_type(8))) short short8;
typedef __attribute__((ext_vector_type(4))) short short4v;
typedef __attribute__((ext_vector_type(4))) float float4v;
typedef __attribute__((ext_vector_type(4))) unsigned short ushort4v;

// ws layout (bytes): WT bf16 [3][8][32][128] @ 0; X16 bf16 [256*176*128] @ 196608
#define WS_WT 0u
#define WS_X  196608u

// LDS (ushort units), total 26496 ush = 52992 B
//  WS @ 0      [3][32][136] = 13056   (phase 1 W slices, padded)
//  KS @ 13056  [176][40]    = 7040    (K, row-major seq x feat)
//  VT @ 20096  [32][200]    = 6400    (V^T, feat x seq; cols 176..191 zeroed)
#define SMEM_TOTAL 26496
#define OFF_KS 13056
#define OFF_VT 20096

__device__ __forceinline__ ushort_t f2bf(float f) {
    union { float f; unsigned int u; } cv; cv.f = f;
    unsigned int u = cv.u;
    unsigned int rb = 0x7FFFu + ((u >> 16) & 1u);   // RTNE
    return (ushort_t)((u + rb) >> 16);
}

// ---------------- k0: one-shot bf16 conversion ----------------------------
__global__ __launch_bounds__(256)
void k0_conv(const float* __restrict__ x,
             const float* __restrict__ Wq, const float* __restrict__ Wk,
             const float* __restrict__ Wv,
             ushort_t* __restrict__ WT, ushort_t* __restrict__ X16)
{
    int bid = blockIdx.x;
    if (bid < 5632) {
        int f4 = bid * 256 + threadIdx.x;
        float4 v = reinterpret_cast<const float4*>(x)[f4];
        ushort4v o;
        o.x = f2bf(v.x); o.y = f2bf(v.y); o.z = f2bf(v.z); o.w = f2bf(v.w);
        reinterpret_cast<ushort4v*>(X16)[f4] = o;
    } else {
        int idx = (bid - 5632) * 256 + threadIdx.x;   // < 24576
        int e = idx * 4;
        int mat = e >> 15, h = (e >> 12) & 7, n = (e >> 7) & 31, k = e & 127;
        const float* W = (mat == 0) ? Wq : ((mat == 1) ? Wk : Wv);
        ushort4v o;
        o.x = f2bf(W[(k + 0) * DMODEL + h * HD + n]);
        o.y = f2bf(W[(k + 1) * DMODEL + h * HD + n]);
        o.z = f2bf(W[(k + 2) * DMODEL + h * HD + n]);
        o.w = f2bf(W[(k + 3) * DMODEL + h * HD + n]);
        reinterpret_cast<ushort4v*>(WT)[idx] = o;
    }
}

// ---------------- k1: fused attention -------------------------------------
__global__ __launch_bounds__(704, 6)
void k1_attn(const ushort_t* __restrict__ X16, const ushort_t* __restrict__ WT,
             const float* __restrict__ bq, const float* __restrict__ bk,
             const float* __restrict__ bv, float* __restrict__ out)
{
    __shared__ ushort_t smem[SMEM_TOTAL];
    ushort_t* WS = smem;                 // [3][32][136]
    ushort_t* KS = smem + OFF_KS;        // [176][40]
    ushort_t* VT = smem + OFF_VT;        // [32][200]

    const int tid  = threadIdx.x;
    const int lane = tid & 63;
    const int w    = tid >> 6;           // wave 0..10 = m-tile / row-tile
    const int c    = lane & 15;
    const int q    = lane >> 4;
    const int b    = blockIdx.x >> 3;
    const int h    = blockIdx.x & 7;

    // ---- stage W-slice (head h): 1536 chunks of 16 B, 16 chunks per n-row
#pragma unroll
    for (int it = 0; it < 3; ++it) {
        int c8 = tid + it * 704;
        if (c8 < 1536) {
            int mat = c8 >> 9, rem = c8 & 511, n = rem >> 4, kc = rem & 15;
            short8 v = *reinterpret_cast<const short8*>(
                WT + (size_t)(((mat * 8 + h) * 32 + n) * 128 + kc * 8));
            *reinterpret_cast<short8*>(WS + (mat * 32 + n) * 136 + kc * 8) = v;
        }
    }
    // zero VT pad cols [176,192) (rows 0..31, 16 cols = 512 threads)
    if (tid < 512) {
        VT[(tid >> 4) * 200 + 176 + (tid & 15)] = 0;
    }
    __syncthreads();   // barrier 0: W staging is cross-wave

    // ---- phase 1: QKV for m-tile w; x fragments direct from global bf16
    const ushort_t* xr = X16 + ((size_t)b * SEQ + w * 16 + c) * DIN;
    short8 xf[4];
#pragma unroll
    for (int kk = 0; kk < 4; ++kk)
        xf[kk] = *reinterpret_cast<const short8*>(xr + kk * 32 + q * 8);

    const float qscale = 0.17677669529663687f * 1.4426950408889634f; // 1/sqrt(32)*log2e

    // Q transposed (A=W, B=x): lane(c,q) gets Q[t=w*16+c][f=nt*16+q*4+r].
    // Packed as one short8 in permuted k-slot order: j<4 -> d=q*4+j,
    // j>=4 -> d=16+q*4+(j-4).
    short8 qf8;
#pragma unroll
    for (int nt = 0; nt < 2; ++nt) {
        const ushort_t* wrow = WS + (nt * 16 + c) * 136 + q * 8;
        float4v acc = {0.f, 0.f, 0.f, 0.f};
#pragma unroll
        for (int kk = 0; kk < 4; ++kk) {
            short8 wf = *reinterpret_cast<const short8*>(wrow + kk * 32);
            acc = __builtin_amdgcn_mfma_f32_16x16x32_bf16(wf, xf[kk], acc, 0, 0, 0);
        }
        float4 bb = *reinterpret_cast<const float4*>(bq + h * HD + nt * 16 + q * 4);
        qf8[nt * 4 + 0] = (short)f2bf((acc[0] + bb.x) * qscale);
        qf8[nt * 4 + 1] = (short)f2bf((acc[1] + bb.y) * qscale);
        qf8[nt * 4 + 2] = (short)f2bf((acc[2] + bb.z) * qscale);
        qf8[nt * 4 + 3] = (short)f2bf((acc[3] + bb.w) * qscale);
    }
    // K normal (A=x, B=W): C = K[t=w*16+q*4+r][d=nt*16+c] -> KS[t][d]
#pragma unroll
    for (int nt = 0; nt < 2; ++nt) {
        const ushort_t* wrow = WS + (32 + nt * 16 + c) * 136 + q * 8;
        float4v acc = {0.f, 0.f, 0.f, 0.f};
#pragma unroll
        for (int kk = 0; kk < 4; ++kk) {
            short8 wf = *reinterpret_cast<const short8*>(wrow + kk * 32);
            acc = __builtin_amdgcn_mfma_f32_16x16x32_bf16(xf[kk], wf, acc, 0, 0, 0);
        }
        float bia = bk[h * HD + nt * 16 + c];
#pragma unroll
        for (int r = 0; r < 4; ++r)
            KS[(w * 16 + q * 4 + r) * 40 + nt * 16 + c] = f2bf(acc[r] + bia);
    }
    // V transposed (A=W, B=x) + ReLU: lane(c,q) -> VT[d=nt*16+q*4+r][t=w*16+c]
#pragma unroll
    for (int nt = 0; nt < 2; ++nt) {
        const ushort_t* wrow = WS + (64 + nt * 16 + c) * 136 + q * 8;
        float4v acc = {0.f, 0.f, 0.f, 0.f};
#pragma unroll
        for (int kk = 0; kk < 4; ++kk) {
            short8 wf = *reinterpret_cast<const short8*>(wrow + kk * 32);
            acc = __builtin_amdgcn_mfma_f32_16x16x32_bf16(wf, xf[kk], acc, 0, 0, 0);
        }
        float4 bb = *reinterpret_cast<const float4*>(bv + h * HD + nt * 16 + q * 4);
#pragma unroll
        for (int r = 0; r < 4; ++r) {
            float bias_r = (r == 0) ? bb.x : (r == 1) ? bb.y : (r == 2) ? bb.z : bb.w;
            float v = acc[r] + bias_r;
            v = v > 0.f ? v : 0.f;
            VT[(nt * 16 + q * 4 + r) * 200 + w * 16 + c] = f2bf(v);
        }
    }
    __syncthreads();   // barrier 1: KS/VT complete

    // ---- phase 2: attention; lane(c,q) owns score column t = w*16+c ----
    const int t_row = w * 16 + c;
    const int lo = (t_row / 22) * 22;    // start of t's 22-joint time block
    float su = 0.f;
    short8 pf[6];                        // P^T fragments, paired n-tiles
    pf[5] = (short8){0, 0, 0, 0, 0, 0, 0, 0};   // n=11 pad half stays zero
#pragma unroll
    for (int n = 0; n < 11; ++n) {
        // A = K row t' = n*16+c, gathered in permuted k-slot order
        const ushort_t* krow = KS + (n * 16 + c) * 40;
        short4v ka = *reinterpret_cast<const short4v*>(krow + q * 4);
        short4v kb = *reinterpret_cast<const short4v*>(krow + 16 + q * 4);
        short8 kf = {ka.x, ka.y, ka.z, ka.w, kb.x, kb.y, kb.z, kb.w};
        float4v s = {0.f, 0.f, 0.f, 0.f};
        s = __builtin_amdgcn_mfma_f32_16x16x32_bf16(kf, qf8, s, 0, 0, 0);
        // S^T[t' = n*16+q*4+r][t = t_row]; mask same-block off-diagonal
#pragma unroll
        for (int r = 0; r < 4; ++r) {
            int tp = n * 16 + q * 4 + r;
            float sv = (((unsigned)(tp - lo) < 22u) && (tp != t_row)) ? -1e30f : s[r];
            float e = __builtin_amdgcn_exp2f(sv);
            su += e;
            pf[n >> 1][(n & 1) * 4 + r] = (short)f2bf(e);
        }
    }
    su += __shfl_xor(su, 16, 64);        // reduce across the 4 quads
    su += __shfl_xor(su, 32, 64);
    const float invs = 1.0f / su;

    // PV: O^T[d][t] = sum_t' V^T[d][t'] P^T[t'][t]; A = V^T pair-gathered
    float* ob = out + ((size_t)b * SEQ + t_row) * DMODEL + h * HD;
#pragma unroll
    for (int mt = 0; mt < 2; ++mt) {
        const ushort_t* vrow = VT + (mt * 16 + c) * 200;
        float4v o = {0.f, 0.f, 0.f, 0.f};
#pragma unroll
        for (int g = 0; g < 6; ++g) {
            short4v va = *reinterpret_cast<const short4v*>(vrow + (2 * g) * 16 + q * 4);
            short4v vb = *reinterpret_cast<const short4v*>(vrow + (2 * g + 1) * 16 + q * 4);
            short8 vf = {va.x, va.y, va.z, va.w, vb.x, vb.y, vb.z, vb.w};
            o = __builtin_amdgcn_mfma_f32_16x16x32_bf16(vf, pf[g], o, 0, 0, 0);
        }
        float4 st;
        st.x = o[0] * invs; st.y = o[1] * invs;
        st.z = o[2] * invs; st.w = o[3] * invs;
        *reinterpret_cast<float4*>(ob + mt * 16 + q * 4) = st;
    }
}

extern "C" void kernel_launch(void* const* d_in, const int* in_sizes, int n_in,
                              void* d_out, int out_size, void* d_ws, size_t ws_size,
                              hipStream_t stream) {
    const float* x  = (const float*)d_in[0];
    const float* Wq = (const float*)d_in[1];
    const float* bq = (const float*)d_in[2];
    const float* Wk = (const float*)d_in[3];
    const float* bk = (const float*)d_in[4];
    const float* Wv = (const float*)d_in[5];
    const float* bv = (const float*)d_in[6];
    float* out = (float*)d_out;

    char* ws = (char*)d_ws;
    ushort_t* WT  = (ushort_t*)(ws + WS_WT);
    ushort_t* X16 = (ushort_t*)(ws + WS_X);

    k0_conv<<<dim3(5728), dim3(256), 0, stream>>>(x, Wq, Wk, Wv, WT, X16);
    k1_attn<<<dim3(2048), dim3(704), 0, stream>>>(X16, WT, bq, bk, bv, out);
}